// Round 1
// baseline (12885.104 us; speedup 1.0000x reference)
//
#include <hip/hip_runtime.h>
#include <math.h>

#define Bb 128
#define Tt 1024
#define Ff 128
#define Hh 256
#define Oo 128
#define Gg 768  // 3*H

// packed weight offsets in d_ws (in floats)
#define OFF_WIH 0          // [32][768][4]   (k-major, float4 per row)
#define OFF_WHH 98304      // [64][768][4]
#define OFF_WSEL 294912    // [64][128][4]
#define OFF_WOUT 327680    // [64][128][4]
#define OFF_PART 360448    // [128] per-block selection partial sums

// Repack row-major [R][K] -> k-major float4 [K/4][R][4]
__global__ void pack_kernel(const float* __restrict__ src, float* __restrict__ dst,
                            int R, int K) {
    int idx = blockIdx.x * 256 + threadIdx.x;
    if (idx >= R * K) return;
    int r = idx / K, k = idx - r * K;
    dst[((k >> 2) * R + r) * 4 + (k & 3)] = src[idx];
}

__device__ __forceinline__ float sigmoidf_(float x) {
    return 1.0f / (1.0f + expf(-x));
}

__global__ __launch_bounds__(256)
void gru_kernel(const float* __restrict__ x, const float* __restrict__ noise,
                const float* __restrict__ bih, const float* __restrict__ bhh,
                const float* __restrict__ bout, const float* __restrict__ bsel,
                const float* __restrict__ ws,
                float* __restrict__ outputs,   // [T,B,O]
                float* __restrict__ selw,      // [T,B,F]
                float* __restrict__ partials)  // [B]
{
    const int b = blockIdx.x;
    const int t = threadIdx.x;   // 0..255, owns hidden dim t

    __shared__ float h_lds[Hh];
    __shared__ float wx_lds[Ff];
    __shared__ float logit_lds[Ff];
    __shared__ float red[256];

    const float4* __restrict__ wih4  = (const float4*)(ws + OFF_WIH);   // [k4*768 + row]
    const float4* __restrict__ whh4  = (const float4*)(ws + OFF_WHH);   // [k4*768 + row]
    const float4* __restrict__ wsel4 = (const float4*)(ws + OFF_WSEL);  // [k4*128 + row]
    const float4* __restrict__ wout4 = (const float4*)(ws + OFF_WOUT);  // [k4*128 + row]
    const float4* __restrict__ wx4 = (const float4*)wx_lds;
    const float4* __restrict__ h4  = (const float4*)h_lds;

    // per-thread biases for its gate rows
    const float c_r = bih[t]        + bhh[t];
    const float c_z = bih[Hh + t]   + bhh[Hh + t];
    const float bin = bih[2*Hh + t];
    const float bhn = bhh[2*Hh + t];
    const float bphase = (t < Oo) ? bout[t] : bsel[t - Oo];

    float ssum = 0.0f;
    float h_old = 0.0f;

    // init: h0 = 0; step-0 input is raw x[:,0]; selection_weights[0] = ones
    h_lds[t] = 0.0f;
    if (t < Ff) {
        wx_lds[t] = x[(size_t)(b * Tt + 0) * Ff + t];
        selw[(size_t)(0 * Bb + b) * Ff + t] = 1.0f;
    }
    __syncthreads();

    for (int step = 0; step < Tt; ++step) {
        // ---- gates: gi = wx @ w_ih^T rows {t,256+t,512+t}; gh = h @ w_hh^T ----
        float ar = 0.f, az = 0.f, an = 0.f;
        #pragma unroll 4
        for (int k = 0; k < Ff / 4; ++k) {
            float4 xv = wx4[k];
            float4 a  = wih4[k * Gg + t];
            float4 bz = wih4[k * Gg + Hh + t];
            float4 c  = wih4[k * Gg + 2*Hh + t];
            ar += a.x*xv.x + a.y*xv.y + a.z*xv.z + a.w*xv.w;
            az += bz.x*xv.x + bz.y*xv.y + bz.z*xv.z + bz.w*xv.w;
            an += c.x*xv.x + c.y*xv.y + c.z*xv.z + c.w*xv.w;
        }
        float hr = 0.f, hz = 0.f, hn = 0.f;
        #pragma unroll 4
        for (int k = 0; k < Hh / 4; ++k) {
            float4 hv = h4[k];
            float4 a  = whh4[k * Gg + t];
            float4 bz = whh4[k * Gg + Hh + t];
            float4 c  = whh4[k * Gg + 2*Hh + t];
            hr += a.x*hv.x + a.y*hv.y + a.z*hv.z + a.w*hv.w;
            hz += bz.x*hv.x + bz.y*hv.y + bz.z*hv.z + bz.w*hv.w;
            hn += c.x*hv.x + c.y*hv.y + c.z*hv.z + c.w*hv.w;
        }
        float r = sigmoidf_(ar + hr + c_r);
        float z = sigmoidf_(az + hz + c_z);
        float n = tanhf(an + bin + r * (hn + bhn));
        float h_new = (1.0f - z) * n + z * h_old;

        __syncthreads();              // everyone done reading h_lds / wx_lds
        h_lds[t] = h_new;
        h_old = h_new;
        __syncthreads();

        // ---- out (threads 0..127) and sel logits (threads 128..255) ----
        {
            float acc = 0.f;
            if (t < Oo) {
                #pragma unroll 4
                for (int k = 0; k < Hh / 4; ++k) {
                    float4 wv = wout4[k * Oo + t];
                    float4 hv = h4[k];
                    acc += wv.x*hv.x + wv.y*hv.y + wv.z*hv.z + wv.w*hv.w;
                }
                outputs[(size_t)(step * Bb + b) * Oo + t] = acc + bphase;
            } else {
                const int r2 = t - Oo;
                #pragma unroll 4
                for (int k = 0; k < Hh / 4; ++k) {
                    float4 wv = wsel4[k * Ff + r2];
                    float4 hv = h4[k];
                    acc += wv.x*hv.x + wv.y*hv.y + wv.z*hv.z + wv.w*hv.w;
                }
                logit_lds[r2] = acc + bphase;
            }
        }
        __syncthreads();

        // ---- selection weights + gated input for next step ----
        if (step + 1 < Tt) {
            if (t < Ff) {
                float lg = logit_lds[t];
                float nz = noise[(size_t)(step * Bb + b) * Ff + t];
                float arg = (lg + logf(nz + 1e-20f) - logf(1.0f - nz + 1e-20f)) * 20.0f;
                float w = sigmoidf_(arg);
                selw[(size_t)((step + 1) * Bb + b) * Ff + t] = w;
                ssum += w;
                wx_lds[t] = w * x[(size_t)(b * Tt + step + 1) * Ff + t];
            }
            __syncthreads();
        }
    }

    // ---- reduce selection sum for this block ----
    red[t] = ssum;
    __syncthreads();
    for (int s = 128; s > 0; s >>= 1) {
        if (t < s) red[t] += red[t + s];
        __syncthreads();
    }
    if (t == 0) partials[b] = red[0];
}

__global__ void finalize_kernel(const float* __restrict__ partials,
                                float* __restrict__ out_scalar) {
    __shared__ float red[128];
    int t = threadIdx.x;
    red[t] = partials[t];
    __syncthreads();
    for (int s = 64; s > 0; s >>= 1) {
        if (t < s) red[t] += red[t + s];
        __syncthreads();
    }
    if (t == 0) out_scalar[0] = red[0];
}

extern "C" void kernel_launch(void* const* d_in, const int* in_sizes, int n_in,
                              void* d_out, int out_size, void* d_ws, size_t ws_size,
                              hipStream_t stream) {
    const float* x     = (const float*)d_in[0];
    const float* noise = (const float*)d_in[1];
    const float* w_ih  = (const float*)d_in[2];
    const float* w_hh  = (const float*)d_in[3];
    const float* b_ih  = (const float*)d_in[4];
    const float* b_hh  = (const float*)d_in[5];
    const float* W_out = (const float*)d_in[6];
    const float* b_out = (const float*)d_in[7];
    const float* W_sel = (const float*)d_in[8];
    const float* b_sel = (const float*)d_in[9];

    float* ws = (float*)d_ws;
    float* out = (float*)d_out;
    float* outputs = out;                              // T*B*O
    float* nsel    = out + (size_t)Tt * Bb * Oo;       // 1
    float* selw    = nsel + 1;                         // T*B*F

    pack_kernel<<<(Gg * Ff + 255) / 256, 256, 0, stream>>>(w_ih, ws + OFF_WIH, Gg, Ff);
    pack_kernel<<<(Gg * Hh + 255) / 256, 256, 0, stream>>>(w_hh, ws + OFF_WHH, Gg, Hh);
    pack_kernel<<<(Ff * Hh + 255) / 256, 256, 0, stream>>>(W_sel, ws + OFF_WSEL, Ff, Hh);
    pack_kernel<<<(Oo * Hh + 255) / 256, 256, 0, stream>>>(W_out, ws + OFF_WOUT, Oo, Hh);

    gru_kernel<<<Bb, 256, 0, stream>>>(x, noise, b_ih, b_hh, b_out, b_sel,
                                       ws, outputs, selw, ws + OFF_PART);

    finalize_kernel<<<1, 128, 0, stream>>>(ws + OFF_PART, nsel);
}

// Round 2
// 5619.157 us; speedup vs baseline: 2.2931x; 2.2931x over previous
//
#include <hip/hip_runtime.h>
#include <math.h>

#define Bb 128
#define Tt 1024
#define Ff 128
#define Hh 256
#define Oo 128

// d_ws layout in 32-bit words
#define OFF_PACK 0u        // 2*192*512 = 196608 packed fp16-pair weights
#define OFF_FLAG 196608u   // 256 flags
#define OFF_HX   196864u   // 2*256*64 = 32768 h-exchange mailboxes
#define OFF_PART 229632u   // 128 float partials

typedef _Float16 half2_t __attribute__((ext_vector_type(2)));
union U32H2 { unsigned int u; half2_t h; };

__device__ __forceinline__ float dot2f(unsigned int wu, unsigned int hu, float acc) {
    U32H2 a, b; a.u = wu; b.u = hu;
#if __has_builtin(__builtin_amdgcn_fdot2)
    return __builtin_amdgcn_fdot2(a.h, b.h, acc, false);
#else
    return acc + (float)a.h.x * (float)b.h.x + (float)a.h.y * (float)b.h.y;
#endif
}

// Pack fp32 weights into per-(role,thread) interleaved fp16 pairs:
// dst[(role*192 + j)*512 + tid]
__global__ void pack_kernel(const float* __restrict__ wih, const float* __restrict__ whh,
                            const float* __restrict__ wsel, const float* __restrict__ wout,
                            unsigned int* __restrict__ dst) {
    int pid = blockIdx.x * 256 + threadIdx.x;
    if (pid >= 2 * 192 * 512) return;
    int tid = pid & 511;
    int j = (pid >> 9) % 192;
    int role = pid / (192 * 512);
    int d = tid & 127, q = tid >> 7, hi = (d >> 6), o = d & 63;
    const float* src; int idx0;
    if (j < 96)       { int g = j >> 5, p = j & 31; int R = g * 256 + role * 128 + d; int cp = 32 * q + p;       src = whh;  idx0 = R * 256 + 2 * cp; }
    else if (j < 144) { int jj = j - 96; int g = jj >> 4, p = jj & 15; int R = g * 256 + role * 128 + d; int cp = 16 * q + p; src = wih; idx0 = R * 128 + 2 * cp; }
    else if (j < 176) { int p = j - 144; int cp = 32 * q + p;                                                   src = wsel; idx0 = d * 256 + 2 * cp; }
    else              { int p = j - 176; int R = role * 64 + o; int cp = 32 * q + 16 * hi + p;                  src = wout; idx0 = R * 256 + 2 * cp; }
    U32H2 v; v.h = (half2_t){ (_Float16)src[idx0], (_Float16)src[idx0 + 1] };
    dst[pid] = v.u;
}

__global__ void zero_flags(unsigned int* __restrict__ flags) {
    flags[threadIdx.x] = 0u;
}

__global__ __launch_bounds__(512, 2)
void gru_kernel(const float* __restrict__ x, const float* __restrict__ noise,
                const float* __restrict__ bih, const float* __restrict__ bhh,
                const float* __restrict__ bout, const float* __restrict__ bsel,
                unsigned int* __restrict__ wsu,
                float* __restrict__ outputs, float* __restrict__ selw,
                float* __restrict__ partials) {
    const int bid = blockIdx.x;
    const int row = bid & 127;
    const int role = bid >> 7;          // pair (row, row+128): same XCD under round-robin
    const int tid = threadIdx.x;
    const int d = tid & 127, q = tid >> 7;
    const int hi = (d >> 6) & 1;

    __shared__ unsigned int h2u[128];   // full h as fp16 pairs
    __shared__ unsigned int wxu[64];    // gated input as fp16 pairs
    __shared__ float red[512 * 5];      // stride-5 padded partials (bank-conflict-free)
    __shared__ float hnewf[128];
    __shared__ float wxf[128];

    // ---- load resident weights into registers (static indexing, fully unrolled) ----
    unsigned int whh2[96], wih2[48], wsel2[32], wout2[16];
    const unsigned int base = (unsigned)(role * 192) * 512u + (unsigned)tid;
    const unsigned int* __restrict__ pk = wsu + OFF_PACK;
    #pragma unroll
    for (int j = 0; j < 96; j++) whh2[j] = pk[base + j * 512];
    #pragma unroll
    for (int j = 0; j < 48; j++) wih2[j] = pk[base + (96 + j) * 512];
    #pragma unroll
    for (int j = 0; j < 32; j++) wsel2[j] = pk[base + (144 + j) * 512];
    #pragma unroll
    for (int j = 0; j < 16; j++) wout2[j] = pk[base + (176 + j) * 512];

    // ---- biases ----
    float bias_r = 0.f, bias_z = 0.f, bias_in = 0.f, bias_hn = 0.f, bsel_d = 0.f, bout_o = 0.f;
    if (tid < 128) {
        int gr = role * 128 + d;
        bias_r  = bih[gr]       + bhh[gr];
        bias_z  = bih[256 + gr] + bhh[256 + gr];
        bias_in = bih[512 + gr];
        bias_hn = bhh[512 + gr];
        bsel_d  = bsel[d];
    } else if (tid < 192) {
        bout_o = bout[role * 64 + (tid - 128)];
    }

    // ---- init state ----
    if (tid < 128) {
        h2u[tid] = 0u;
        wxf[tid] = x[((size_t)row * Tt) * Ff + tid];
        if (role == 0) selw[(size_t)row * Ff + tid] = 1.0f;   // selection_weights[0] = ones
    }
    __syncthreads();
    if (tid < 64) {
        U32H2 v; v.h = (half2_t){ (_Float16)wxf[2 * tid], (_Float16)wxf[2 * tid + 1] };
        wxu[tid] = v.u;
    }
    __syncthreads();

    unsigned int* flags = wsu + OFF_FLAG;
    unsigned int* hx    = wsu + OFF_HX;
    unsigned int* myflag = &flags[row * 2 + role];
    unsigned int* pflag  = &flags[row * 2 + (role ^ 1)];

    float h_old = 0.f, ssum = 0.f;
    size_t xbase  = ((size_t)row * Tt + 1) * Ff + d;
    size_t nzbase = (size_t)row * Ff + d;
    size_t swbase = ((size_t)Bb + row) * Ff + d;
    size_t obase  = (size_t)row * Oo + role * 64 + ((tid >= 128) ? (tid - 128) : 0);

    const uint4* h4 = (const uint4*)h2u;
    const uint4* w4 = (const uint4*)wxu;

    for (int t = 0; t < Tt; ++t) {
        // ---- G: gate partials (own gate rows, own k-quarter) ----
        float a_r = 0.f, a_z = 0.f, a_in = 0.f, a_hn = 0.f;
        #pragma unroll
        for (int pp = 0; pp < 8; ++pp) {
            uint4 hv = h4[8 * q + pp];
            unsigned hh[4] = { hv.x, hv.y, hv.z, hv.w };
            #pragma unroll
            for (int i = 0; i < 4; i++) {
                a_r  = dot2f(whh2[pp * 4 + i],      hh[i], a_r);
                a_z  = dot2f(whh2[32 + pp * 4 + i], hh[i], a_z);
                a_hn = dot2f(whh2[64 + pp * 4 + i], hh[i], a_hn);
            }
        }
        #pragma unroll
        for (int pp = 0; pp < 4; ++pp) {
            uint4 wv = w4[4 * q + pp];
            unsigned ww[4] = { wv.x, wv.y, wv.z, wv.w };
            #pragma unroll
            for (int i = 0; i < 4; i++) {
                a_r  = dot2f(wih2[pp * 4 + i],      ww[i], a_r);
                a_z  = dot2f(wih2[16 + pp * 4 + i], ww[i], a_z);
                a_in = dot2f(wih2[32 + pp * 4 + i], ww[i], a_in);
            }
        }
        red[tid * 5 + 0] = a_r; red[tid * 5 + 1] = a_z;
        red[tid * 5 + 2] = a_in; red[tid * 5 + 3] = a_hn;
        __syncthreads();                               // B1

        // ---- H: finalize own h-half ----
        if (tid < 128) {
            float rr = bias_r, zz = bias_z, ii = bias_in, hh = bias_hn;
            #pragma unroll
            for (int qq = 0; qq < 4; qq++) {
                int b0 = (qq * 128 + d) * 5;
                rr += red[b0]; zz += red[b0 + 1]; ii += red[b0 + 2]; hh += red[b0 + 3];
            }
            float r = 1.f / (1.f + expf(-rr));
            float z = 1.f / (1.f + expf(-zz));
            float n = tanhf(ii + r * hh);
            float hn2 = (1.f - z) * n + z * h_old;
            h_old = hn2;
            hnewf[d] = hn2;
        }
        __syncthreads();                               // B2
        if (tid < 64) {
            U32H2 v; v.h = (half2_t){ (_Float16)hnewf[2 * tid], (_Float16)hnewf[2 * tid + 1] };
            h2u[role * 64 + tid] = v.u;
            __hip_atomic_store(&hx[(((t & 1) * 256 + row * 2 + role) * 64) + tid], v.u,
                               __ATOMIC_RELAXED, __HIP_MEMORY_SCOPE_AGENT);
        }
        __syncthreads();                               // B3: all publish stores done
        if (tid == 0) {
            __hip_atomic_store(myflag, (unsigned)(t + 1), __ATOMIC_RELEASE, __HIP_MEMORY_SCOPE_AGENT);
            while (__hip_atomic_load(pflag, __ATOMIC_ACQUIRE, __HIP_MEMORY_SCOPE_AGENT) < (unsigned)(t + 1))
                __builtin_amdgcn_s_sleep(1);
        }
        __syncthreads();                               // B4
        if (tid < 64) {
            unsigned pv = __hip_atomic_load(&hx[(((t & 1) * 256 + row * 2 + (role ^ 1)) * 64) + tid],
                                            __ATOMIC_RELAXED, __HIP_MEMORY_SCOPE_AGENT);
            h2u[(role ^ 1) * 64 + tid] = pv;
        }
        __syncthreads();                               // B5

        // ---- P: sel (full, duplicated) + out (own half) partials ----
        float s_acc = 0.f, o_acc = 0.f;
        #pragma unroll
        for (int pp = 0; pp < 8; ++pp) {
            uint4 hv = h4[8 * q + pp];
            unsigned hh2[4] = { hv.x, hv.y, hv.z, hv.w };
            #pragma unroll
            for (int i = 0; i < 4; i++) s_acc = dot2f(wsel2[pp * 4 + i], hh2[i], s_acc);
            if ((pp >> 2) == hi) {
                #pragma unroll
                for (int i = 0; i < 4; i++) o_acc = dot2f(wout2[(pp & 3) * 4 + i], hh2[i], o_acc);
            }
        }
        red[tid * 5 + 0] = s_acc; red[tid * 5 + 1] = o_acc;
        __syncthreads();                               // B6

        if (tid >= 128 && tid < 192) {
            int oo = tid - 128; float acc = bout_o;
            #pragma unroll
            for (int qq = 0; qq < 4; qq++)
                acc += red[(qq * 128 + oo) * 5 + 1] + red[(qq * 128 + 64 + oo) * 5 + 1];
            outputs[obase] = acc;
        }
        if (tid < 128 && t < Tt - 1) {
            float lg = bsel_d;
            #pragma unroll
            for (int qq = 0; qq < 4; qq++) lg += red[(qq * 128 + d) * 5 + 0];
            float nz = noise[nzbase];
            float arg = (lg + logf(nz + 1e-20f) - logf(1.f - nz + 1e-20f)) * 20.0f;
            float w = 1.f / (1.f + expf(-arg));
            if (role == 0) { selw[swbase] = w; ssum += w; }
            wxf[d] = w * x[xbase];
        }
        __syncthreads();                               // B7
        if (t < Tt - 1 && tid < 64) {
            U32H2 v; v.h = (half2_t){ (_Float16)wxf[2 * tid], (_Float16)wxf[2 * tid + 1] };
            wxu[tid] = v.u;
        }
        __syncthreads();                               // B8

        obase += (size_t)Bb * Oo; nzbase += (size_t)Bb * Ff;
        swbase += (size_t)Bb * Ff; xbase += Ff;
    }

    // ---- per-row selection-sum partial (role A only) ----
    __syncthreads();
    if (role == 0) {
        red[tid] = (tid < 128) ? ssum : 0.f;
        __syncthreads();
        for (int s = 256; s > 0; s >>= 1) {
            if (tid < s) red[tid] += red[tid + s];
            __syncthreads();
        }
        if (tid == 0) partials[row] = red[0];
    }
}

__global__ void finalize_kernel(const float* __restrict__ partials, float* __restrict__ out_scalar) {
    __shared__ float red[128];
    int t = threadIdx.x;
    red[t] = partials[t];
    __syncthreads();
    for (int s = 64; s > 0; s >>= 1) {
        if (t < s) red[t] += red[t + s];
        __syncthreads();
    }
    if (t == 0) out_scalar[0] = red[0];
}

extern "C" void kernel_launch(void* const* d_in, const int* in_sizes, int n_in,
                              void* d_out, int out_size, void* d_ws, size_t ws_size,
                              hipStream_t stream) {
    const float* x     = (const float*)d_in[0];
    const float* noise = (const float*)d_in[1];
    const float* w_ih  = (const float*)d_in[2];
    const float* w_hh  = (const float*)d_in[3];
    const float* b_ih  = (const float*)d_in[4];
    const float* b_hh  = (const float*)d_in[5];
    const float* W_out = (const float*)d_in[6];
    const float* b_out = (const float*)d_in[7];
    const float* W_sel = (const float*)d_in[8];
    const float* b_sel = (const float*)d_in[9];

    unsigned int* wsu = (unsigned int*)d_ws;
    float* out = (float*)d_out;
    float* outputs = out;                               // [T,B,O]
    float* nsel    = out + (size_t)Tt * Bb * Oo;        // scalar
    float* selw    = nsel + 1;                          // [T,B,F]
    float* partials = (float*)(wsu + OFF_PART);

    pack_kernel<<<(2 * 192 * 512 + 255) / 256, 256, 0, stream>>>(w_ih, w_hh, W_sel, W_out, wsu + OFF_PACK);
    zero_flags<<<1, 256, 0, stream>>>(wsu + OFF_FLAG);
    gru_kernel<<<256, 512, 0, stream>>>(x, noise, b_ih, b_hh, b_out, b_sel,
                                        wsu, outputs, selw, partials);
    finalize_kernel<<<1, 128, 0, stream>>>(partials, nsel);
}